// Round 11
// baseline (305.702 us; speedup 1.0000x reference)
//
#include <hip/hip_runtime.h>
#include <math.h>

#define NN 11
#define RR 8192               // B*L positions
#define DD 1024
#define EPSV 1e-5f
#define PREP_TPB 256

// ---- ws layout (floats) ----
// wvec  : [22][1024] f32   @ 0       (q*gamma; attn 0..10, mlp 0..10)
// scal  : [22][2]    f32   @ 22528   (sum(q*g), sum(q*b)); padded to 64
// wfrag : [32][2][64][8] bf16 @ 22592 (prepacked B frags; 32768 shorts = 16384 float-slots)
// dots  : [24][11][8192]   @ 38976   (j: 0..21 dots, 22 sum, 23 ssq)
// pack  : [8192][264]      @ 2201664
#define OFF_SCAL 22528
#define OFF_WFRAG 22592
#define OFF_DOTS 38976
#define OFF_PACK 2201664

typedef __attribute__((ext_vector_type(8))) short short8;
typedef __attribute__((ext_vector_type(4))) float f32x4;

__device__ __forceinline__ float wave_reduce(float v) {
#pragma unroll
  for (int o = 32; o > 0; o >>= 1) v += __shfl_xor(v, o, 64);
  return v;
}

__device__ __forceinline__ float dot4(const float4 a, const float4 b) {
  return a.x*b.x + a.y*b.y + a.z*b.z + a.w*b.w;
}

__device__ __forceinline__ unsigned bf2(float a, float b) {
  unsigned ua = __float_as_uint(a), ub = __float_as_uint(b);
  ua = (ua + 0x7FFFu + ((ua >> 16) & 1u)) >> 16;
  ub = (ub + 0x7FFFu + ((ub >> 16) & 1u)) >> 16;
  return ua | (ub << 16);
}

__global__ __launch_bounds__(PREP_TPB) void prep_kernel(
    const float* __restrict__ aq, const float* __restrict__ ag, const float* __restrict__ ab,
    const float* __restrict__ mq, const float* __restrict__ mg, const float* __restrict__ mb,
    float* __restrict__ wvec, float* __restrict__ scal)
{
  const int j = blockIdx.x;              // 0..21
  const float *q, *g, *bt;
  if (j < NN) { q = aq + (size_t)j*DD;      g = ag + (size_t)j*DD;      bt = ab + (size_t)j*DD; }
  else        { q = mq + (size_t)(j-NN)*DD; g = mg + (size_t)(j-NN)*DD; bt = mb + (size_t)(j-NN)*DD; }
  const int t = threadIdx.x;
  float sqg = 0.f, sqb = 0.f;
  for (int d = t; d < DD; d += PREP_TPB) {
    float qq = q[d];
    float w  = qq * g[d];
    wvec[(size_t)j*DD + d] = w;
    sqg += w;
    sqb += qq * bt[d];
  }
  sqg = wave_reduce(sqg);
  sqb = wave_reduce(sqb);
  __shared__ float red[2][PREP_TPB/64];
  const int lane = t & 63, wid = t >> 6;
  if (lane == 0) { red[0][wid] = sqg; red[1][wid] = sqb; }
  __syncthreads();
  if (t == 0) {
    float a = 0.f, b2 = 0.f;
    for (int w = 0; w < PREP_TPB/64; ++w) { a += red[0][w]; b2 += red[1][w]; }
    scal[2*j]   = a;
    scal[2*j+1] = b2;
  }
}

// pack B fragments: wfrag[kstep][c][lane][e] = bf16(wvec[j][k]), j=c*16+(lane&15),
// k=kstep*32+(lane>>4)*8+e; j>=22 -> 0. Same (lane,e)->k map as the A-frag pack,
// so the MFMA contraction is invariant to the exact HW k permutation.
__global__ __launch_bounds__(256) void prep2_kernel(
    const float* __restrict__ wvec, short* __restrict__ wfrag)
{
  const int kstep = blockIdx.x;          // 0..31
  const int t = threadIdx.x;
#pragma unroll
  for (int q = 0; q < 4; ++q) {
    const int idx  = t*4 + q;            // 0..1023
    const int c    = idx >> 9;
    const int lane = (idx >> 3) & 63;
    const int e    = idx & 7;
    const int k    = kstep*32 + (lane >> 4)*8 + e;
    const int j    = c*16 + (lane & 15);
    float v = (j < 22) ? wvec[(size_t)j*DD + k] : 0.f;
    unsigned u = __float_as_uint(v);
    u = (u + 0x7FFFu + ((u >> 16) & 1u)) >> 16;
    wfrag[(size_t)kstep*1024 + idx] = (short)u;
  }
}

__device__ __forceinline__ void commit_stage(short* tileHalf, const float4* st,
    float* ssqp, float* sump, int srow, int scol)
{
#pragma unroll
  for (int i = 0; i < 8; ++i) {
    float4 v = st[i];
    sump[i] += v.x + v.y + v.z + v.w;
    ssqp[i] = fmaf(v.x, v.x, ssqp[i]);
    ssqp[i] = fmaf(v.y, v.y, ssqp[i]);
    ssqp[i] = fmaf(v.z, v.z, ssqp[i]);
    ssqp[i] = fmaf(v.w, v.w, ssqp[i]);
    const int row  = 8*i + srow;
    const int byte = row*256 + scol*8;
    const int swz  = byte ^ ((row & 7) << 4);
    *(uint2*)((char*)tileHalf + swz) = make_uint2(bf2(v.x, v.y), bf2(v.z, v.w));
  }
}

// K1: MFMA dots. Block = 64 rows (one n, 64 positions) x K=1024 in 8 LDS
// rounds of 128. Stage f32->bf16 into XOR-swizzled LDS (stats in f32 on the
// way through); 4 waves each own 16 rows; per K-step: 1 ds_read_b128 A-frag +
// 2 coalesced L2 B-frag loads + 2 MFMA. Double-buffered, 1 barrier/round.
__global__ __launch_bounds__(256) void dots_kernel(
    const float* __restrict__ streams, const short* __restrict__ wfrag,
    float* __restrict__ dots)
{
  __shared__ __align__(16) short tile[16384];  // 32 KB: two 16KB halves [64 rows][128 k] bf16

  const int n   = blockIdx.x / 128;
  const int p0  = (blockIdx.x % 128) * 64;
  const int t   = threadIdx.x;
  const int l   = t & 63;
  const int wv  = t >> 6;                // wave 0..3 -> rows [16wv, 16wv+16)
  const int g   = l >> 4;                // 0..3
  const int lr  = l & 15;
  const int srow = t >> 5;               // staging: row-within-8-group
  const int scol = t & 31;               // staging: float4 col

  float ssqp[8], sump[8];
#pragma unroll
  for (int i = 0; i < 8; ++i) { ssqp[i] = 0.f; sump[i] = 0.f; }
  f32x4 acc0 = {0.f,0.f,0.f,0.f};
  f32x4 acc1 = {0.f,0.f,0.f,0.f};

  float4 st[8];
  // ---- prologue: stage chunk 0 into half 0 ----
#pragma unroll
  for (int i = 0; i < 8; ++i)
    st[i] = *(const float4*)(streams + ((size_t)(n*RR + p0 + 8*i + srow))*DD + scol*4);
  commit_stage(tile, st, ssqp, sump, srow, scol);
  __syncthreads();

  // A-frag swizzled byte offset within a half (row fixed per thread)
  const int arow  = wv*16 + lr;
  const int abase = (arow*256);          // + ks*64 + g*16, then XOR

  for (int kc = 0; kc < 8; ++kc) {
    short* curh = tile + ((kc & 1) ? 8192 : 0);
    short* nxth = tile + ((kc & 1) ? 0 : 8192);

    if (kc < 7) {
#pragma unroll
      for (int i = 0; i < 8; ++i)
        st[i] = *(const float4*)(streams + ((size_t)(n*RR + p0 + 8*i + srow))*DD + (kc+1)*128 + scol*4);
    }

#pragma unroll
    for (int ks = 0; ks < 4; ++ks) {
      const int byte = abase + ks*64 + g*16;
      const int swz  = byte ^ ((arow & 7) << 4);
      short8 af = *(short8*)((char*)curh + swz);
      const size_t bo = (size_t)(kc*4 + ks)*1024 + (size_t)l*8;
      short8 b0 = *(const short8*)(wfrag + bo);
      short8 b1 = *(const short8*)(wfrag + bo + 512);
      acc0 = __builtin_amdgcn_mfma_f32_16x16x32_bf16(af, b0, acc0, 0, 0, 0);
      acc1 = __builtin_amdgcn_mfma_f32_16x16x32_bf16(af, b1, acc1, 0, 0, 0);
    }

    if (kc < 7) {
      commit_stage(nxth, st, ssqp, sump, srow, scol);
      __syncthreads();
    }
  }

  // ---- epilogue: transpose C + stats via LDS, coalesced dots store ----
  __syncthreads();
  float* fl   = (float*)tile;            // Cs[64][33] @ 0 (2112 floats)
  float* fssq = fl + 2112;               // [64][32]
  float* fsum = fl + 2112 + 2048;        // [64][32]
#pragma unroll
  for (int r = 0; r < 4; ++r) {
    fl[(wv*16 + g*4 + r)*33 + lr]      = acc0[r];
    fl[(wv*16 + g*4 + r)*33 + 16 + lr] = acc1[r];
  }
#pragma unroll
  for (int i = 0; i < 8; ++i) {
    fssq[(8*i + srow)*32 + scol] = ssqp[i];
    fsum[(8*i + srow)*32 + scol] = sump[i];
  }
  __syncthreads();
  if (t < 64) {
    float s1 = 0.f, s2 = 0.f;
#pragma unroll
    for (int c2 = 0; c2 < 32; ++c2) { s1 += fsum[t*32 + c2]; s2 += fssq[t*32 + c2]; }
    fl[t*33 + 22] = s1;
    fl[t*33 + 23] = s2;
  }
  __syncthreads();
#pragma unroll
  for (int q = 0; q < 6; ++q) {
    const int o   = t*6 + q;             // 0..1535
    const int row = o / 24;
    const int j   = o % 24;
    dots[((size_t)j*NN + n)*RR + p0 + row] = fl[row*33 + j];
  }
}

// K2: one thread per position. Softmax pass-1 weights, pass-2 logit pieces.
__global__ __launch_bounds__(256) void coef_kernel(
    const float* __restrict__ dots, const float* __restrict__ scal,
    float* __restrict__ pack)
{
  const int p = blockIdx.x*256 + threadIdx.x;      // 8192 threads exactly
  float mu[NN], rs[NN];
#pragma unroll
  for (int n = 0; n < NN; ++n) {
    float s  = dots[((size_t)22*NN + n)*RR + p];
    float q2 = dots[((size_t)23*NN + n)*RR + p];
    mu[n] = s * (1.f/DD);
    rs[n] = rsqrtf(q2*(1.f/DD) - mu[n]*mu[n] + EPSV);
  }
  float* pk = pack + (size_t)p*264;
  for (int i = 0; i < NN; ++i) {                   // uniform runtime i
    const float qgA = scal[2*i],        qbA = scal[2*i+1];
    const float qgM = scal[2*(NN+i)],   qbM = scal[2*(NN+i)+1];
    float w1[NN];
    float mx = -3.0e38f;
#pragma unroll
    for (int n = 0; n < NN; ++n) if (n <= i) {
      float dA = dots[((size_t)i*NN + n)*RR + p];
      float lg = (dA - mu[n]*qgA)*rs[n] + qbA;
      w1[n] = lg;
      mx = fmaxf(mx, lg);
    }
    float S = 0.f;
#pragma unroll
    for (int n = 0; n < NN; ++n) if (n <= i) { float e = __expf(w1[n]-mx); w1[n] = e; S += e; }
    float inv = 1.f/S;
    float muh = 0.f, hd = 0.f;
#pragma unroll
    for (int n = 0; n < NN; ++n) if (n <= i) {
      w1[n] *= inv;
      float dM = dots[((size_t)(NN+i)*NN + n)*RR + p];
      muh += w1[n]*mu[n];
      hd  += w1[n]*dM;
      pk[i*NN + n] = w1[n];
      if (n < i) pk[121 + i*NN + n] = (dM - mu[n]*qgM)*rs[n] + qbM;
    }
    pk[242 + i] = hd - muh*qgM;
    pk[253 + i] = muh;
  }
}

// K3: one block per position: h sumsq (11 wave reduces), finish logits,
// build C row, combine to out. Streams read once, out written once.
__global__ __launch_bounds__(256) void combine_kernel(
    const float* __restrict__ streams,
    const float* __restrict__ pack,
    const float* __restrict__ scal,
    float* __restrict__ out)
{
  __shared__ float P[264];
  __shared__ float red[4][12];
  __shared__ float C[121];

  const int p = blockIdx.x;
  const int t = threadIdx.x;
  const int lane = t & 63, w = t >> 6;

  for (int s = t; s < 264; s += 256) P[s] = pack[(size_t)p*264 + s];

  float4 x[NN];
#pragma unroll
  for (int n = 0; n < NN; ++n)
    x[n] = *(const float4*)(streams + ((size_t)n*RR + p)*DD + 4*t);
  __syncthreads();

  float hss[NN];
#pragma unroll
  for (int i = 0; i < NN; ++i) {
    float4 h = make_float4(0.f,0.f,0.f,0.f);
#pragma unroll
    for (int n = 0; n < NN; ++n) if (n <= i) {
      float wv = P[i*NN + n];
      h.x = fmaf(wv, x[n].x, h.x);
      h.y = fmaf(wv, x[n].y, h.y);
      h.z = fmaf(wv, x[n].z, h.z);
      h.w = fmaf(wv, x[n].w, h.w);
    }
    hss[i] = dot4(h, h);
  }
#pragma unroll
  for (int i = 0; i < NN; ++i) hss[i] = wave_reduce(hss[i]);
  if (lane == 0) {
#pragma unroll
    for (int i = 0; i < NN; ++i) red[w][i] = hss[i];
  }
  __syncthreads();

  if (t < NN) {
    const int i = t;
    float hs   = red[0][i] + red[1][i] + red[2][i] + red[3][i];
    float mu_h = P[253 + i];
    float Ahd  = P[242 + i];
    float varh = hs*(1.f/DD) - mu_h*mu_h;
    float rsh  = rsqrtf(varh + EPSV);
    float qbM  = scal[2*(NN+i)+1];
    float lgh  = Ahd*rsh + qbM;

    float mx2 = lgh;
#pragma unroll
    for (int n = 0; n < NN; ++n) if (n < i) mx2 = fmaxf(mx2, P[121 + i*NN + n]);
    float w2[NN];
    float eh = __expf(lgh - mx2);
    float S2 = eh;
#pragma unroll
    for (int n = 0; n < NN; ++n) if (n < i) {
      float e = __expf(P[121 + i*NN + n] - mx2);
      w2[n] = e;
      S2 += e;
    }
    float inv2 = 1.f/S2;
    float ehw  = eh*inv2;
#pragma unroll
    for (int n = 0; n < NN; ++n) {
      float cc = 0.f;
      if (n < i)  cc = w2[n]*inv2;
      if (n <= i) cc += ehw*P[i*NN + n];
      C[i*NN + n] = cc;
    }
  }
  __syncthreads();

#pragma unroll
  for (int i = 0; i < NN; ++i) {
    float4 o = make_float4(0.f,0.f,0.f,0.f);
#pragma unroll
    for (int n = 0; n < NN; ++n) {
      float cc = C[i*NN + n];
      o.x = fmaf(cc, x[n].x, o.x);
      o.y = fmaf(cc, x[n].y, o.y);
      o.z = fmaf(cc, x[n].z, o.z);
      o.w = fmaf(cc, x[n].w, o.w);
    }
    *(float4*)(out + ((size_t)i*RR + p)*DD + 4*t) = o;
  }
}

extern "C" void kernel_launch(void* const* d_in, const int* in_sizes, int n_in,
                              void* d_out, int out_size, void* d_ws, size_t ws_size,
                              hipStream_t stream) {
  const float* streams = (const float*)d_in[0];
  const float* aq = (const float*)d_in[1];
  const float* ag = (const float*)d_in[2];
  const float* ab = (const float*)d_in[3];
  const float* mq = (const float*)d_in[4];
  const float* mg = (const float*)d_in[5];
  const float* mb = (const float*)d_in[6];
  float* outp = (float*)d_out;

  float* wsf   = (float*)d_ws;
  float* wvec  = wsf;
  float* scal  = wsf + OFF_SCAL;
  short* wfrag = (short*)(wsf + OFF_WFRAG);
  float* dots  = wsf + OFF_DOTS;
  float* pack  = wsf + OFF_PACK;

  prep_kernel<<<dim3(2*NN), dim3(PREP_TPB), 0, stream>>>(aq, ag, ab, mq, mg, mb, wvec, scal);
  prep2_kernel<<<dim3(32), dim3(256), 0, stream>>>(wvec, wfrag);
  dots_kernel<<<dim3(NN*128), dim3(256), 0, stream>>>(streams, wfrag, dots);
  coef_kernel<<<dim3(RR/256), dim3(256), 0, stream>>>(dots, scal, pack);
  combine_kernel<<<dim3(RR), dim3(256), 0, stream>>>(streams, pack, scal, outp);
}

// Round 13
// 261.563 us; speedup vs baseline: 1.1688x; 1.1688x over previous
//
#include <hip/hip_runtime.h>
#include <math.h>

#define NN 11
#define RR 8192               // B*L positions
#define DD 1024
#define EPSV 1e-5f
#define PREP_TPB 256
#define KPARTS 2

// ---- ws layout (floats) ----
// wvec  : [22][1024] f32   @ 0
// scal  : [22][2]    f32   @ 22528 (padded to 64)
// wfrag : [32][2][64][8] bf16 @ 22592 (32768 shorts = 16384 float-slots)
// dotsp : [2][24][11][8192] @ 38976  (per-kpart partials; j:0..21 dots, 22 sum, 23 ssq)
// pack  : [8192][264]       @ 4364352
#define OFF_SCAL 22528
#define OFF_WFRAG 22592
#define OFF_DOTS 38976
#define OFF_PACK 4364352

typedef __attribute__((ext_vector_type(8))) short short8;
typedef __attribute__((ext_vector_type(4))) float f32x4;

__device__ __forceinline__ float wave_reduce(float v) {
#pragma unroll
  for (int o = 32; o > 0; o >>= 1) v += __shfl_xor(v, o, 64);
  return v;
}

__device__ __forceinline__ float dot4(const float4 a, const float4 b) {
  return a.x*b.x + a.y*b.y + a.z*b.z + a.w*b.w;
}

__device__ __forceinline__ unsigned bf2(float a, float b) {
  unsigned ua = __float_as_uint(a), ub = __float_as_uint(b);
  ua = (ua + 0x7FFFu + ((ua >> 16) & 1u)) >> 16;
  ub = (ub + 0x7FFFu + ((ub >> 16) & 1u)) >> 16;
  return ua | (ub << 16);
}

__global__ __launch_bounds__(PREP_TPB) void prep_kernel(
    const float* __restrict__ aq, const float* __restrict__ ag, const float* __restrict__ ab,
    const float* __restrict__ mq, const float* __restrict__ mg, const float* __restrict__ mb,
    float* __restrict__ wvec, float* __restrict__ scal)
{
  const int j = blockIdx.x;              // 0..21
  const float *q, *g, *bt;
  if (j < NN) { q = aq + (size_t)j*DD;      g = ag + (size_t)j*DD;      bt = ab + (size_t)j*DD; }
  else        { q = mq + (size_t)(j-NN)*DD; g = mg + (size_t)(j-NN)*DD; bt = mb + (size_t)(j-NN)*DD; }
  const int t = threadIdx.x;
  float sqg = 0.f, sqb = 0.f;
  for (int d = t; d < DD; d += PREP_TPB) {
    float qq = q[d];
    float w  = qq * g[d];
    wvec[(size_t)j*DD + d] = w;
    sqg += w;
    sqb += qq * bt[d];
  }
  sqg = wave_reduce(sqg);
  sqb = wave_reduce(sqb);
  __shared__ float red[2][PREP_TPB/64];
  const int lane = t & 63, wid = t >> 6;
  if (lane == 0) { red[0][wid] = sqg; red[1][wid] = sqb; }
  __syncthreads();
  if (t == 0) {
    float a = 0.f, b2 = 0.f;
    for (int w = 0; w < PREP_TPB/64; ++w) { a += red[0][w]; b2 += red[1][w]; }
    scal[2*j]   = a;
    scal[2*j+1] = b2;
  }
}

// pack B fragments: wfrag[kstep][c][lane][e] = bf16(wvec[j][k]), j=c*16+(lane&15),
// k=kstep*32+(lane>>4)*8+e; j>=22 -> 0.
__global__ __launch_bounds__(256) void prep2_kernel(
    const float* __restrict__ wvec, short* __restrict__ wfrag)
{
  const int kstep = blockIdx.x;          // 0..31
  const int t = threadIdx.x;
#pragma unroll
  for (int q = 0; q < 4; ++q) {
    const int idx  = t*4 + q;            // 0..1023
    const int c    = idx >> 9;
    const int lane = (idx >> 3) & 63;
    const int e    = idx & 7;
    const int k    = kstep*32 + (lane >> 4)*8 + e;
    const int j    = c*16 + (lane & 15);
    float v = (j < 22) ? wvec[(size_t)j*DD + k] : 0.f;
    unsigned u = __float_as_uint(v);
    u = (u + 0x7FFFu + ((u >> 16) & 1u)) >> 16;
    wfrag[(size_t)kstep*1024 + idx] = (short)u;
  }
}

// K1: MFMA dots, NO stream staging. Block = (n, 64 pos, kpart of K=512).
// A-frags gathered directly from global (lane l: row p0+wv*16+(l&15), 32B at
// k=(l>>4)*8), cvt f32->bf16 in-register; B (wfrag kpart slice, 32 KB) lives
// in LDS, read conflict-free. Zero barriers in the K loop; loads pipeline on
// vmcnt. Stats ride the same registers (rows wave-private -> 2 shuffles).
__global__ __launch_bounds__(256) void dots_kernel(
    const float* __restrict__ streams, const short* __restrict__ wfrag,
    float* __restrict__ dotsp)
{
  __shared__ __align__(16) short lwf[16384];   // 32 KB: wfrag slice [16 ks][2 ct][64 lane][8]

  const int bid   = blockIdx.x;          // 11 * 128 * 2 = 2816
  const int n     = bid / 256;
  const int rem   = bid % 256;
  const int p0    = (rem >> 1) * 64;
  const int kpart = rem & 1;
  const int t  = threadIdx.x;
  const int l  = t & 63;
  const int wv = t >> 6;                 // wave 0..3 -> rows [16wv,16wv+16)
  const int lr = l & 15;
  const int g  = l >> 4;                 // 0..3

  // ---- preload B slice into LDS (coalesced): 2048 short8 = 8 per thread ----
  {
    const short8* src = (const short8*)(wfrag + (size_t)kpart*16384);
    short8* dst = (short8*)lwf;
#pragma unroll
    for (int q = 0; q < 8; ++q) dst[t*8 + q] = src[t*8 + q];
  }
  __syncthreads();

  const float* rowp = streams + ((size_t)(n*RR + p0 + wv*16 + lr))*DD + kpart*512;

  f32x4 acc0 = {0.f,0.f,0.f,0.f};
  f32x4 acc1 = {0.f,0.f,0.f,0.f};
  float sum = 0.f, ssq = 0.f;

  float4 a0 = *(const float4*)(rowp + g*8);
  float4 a1 = *(const float4*)(rowp + g*8 + 4);

#pragma unroll
  for (int ks = 0; ks < 16; ++ks) {
    float4 n0, n1;
    if (ks < 15) {
      n0 = *(const float4*)(rowp + (ks+1)*32 + g*8);
      n1 = *(const float4*)(rowp + (ks+1)*32 + g*8 + 4);
    }
    // stats (f32 exact)
    sum += a0.x + a0.y + a0.z + a0.w + a1.x + a1.y + a1.z + a1.w;
    ssq = fmaf(a0.x,a0.x, ssq); ssq = fmaf(a0.y,a0.y, ssq);
    ssq = fmaf(a0.z,a0.z, ssq); ssq = fmaf(a0.w,a0.w, ssq);
    ssq = fmaf(a1.x,a1.x, ssq); ssq = fmaf(a1.y,a1.y, ssq);
    ssq = fmaf(a1.z,a1.z, ssq); ssq = fmaf(a1.w,a1.w, ssq);
    // cvt to bf16 A-frag
    union { short8 s; uint4 u; } cv;
    cv.u = make_uint4(bf2(a0.x,a0.y), bf2(a0.z,a0.w), bf2(a1.x,a1.y), bf2(a1.z,a1.w));
    // B frags from LDS (lane-stride 16B, conflict-free)
    short8 b0 = *(const short8*)(lwf + ks*1024 + l*8);
    short8 b1 = *(const short8*)(lwf + ks*1024 + 512 + l*8);
    acc0 = __builtin_amdgcn_mfma_f32_16x16x32_bf16(cv.s, b0, acc0, 0, 0, 0);
    acc1 = __builtin_amdgcn_mfma_f32_16x16x32_bf16(cv.s, b1, acc1, 0, 0, 0);
    a0 = n0; a1 = n1;
  }

  // ---- stats: reduce over the 4 k-slice lanes (l, l^16, l^32, l^48) ----
  sum += __shfl_xor(sum, 16, 64); sum += __shfl_xor(sum, 32, 64);
  ssq += __shfl_xor(ssq, 16, 64); ssq += __shfl_xor(ssq, 32, 64);

  // ---- epilogue: C + stats -> fl[64][33] in reused LDS, coalesced store ----
  __syncthreads();                        // all waves done reading lwf
  float* fl = (float*)lwf;
#pragma unroll
  for (int r = 0; r < 4; ++r) {
    fl[(wv*16 + g*4 + r)*33 + lr]      = acc0[r];
    fl[(wv*16 + g*4 + r)*33 + 16 + lr] = acc1[r];
  }
  if (g == 0) {                           // lanes 0..15: row wv*16+lr totals
    fl[(wv*16 + lr)*33 + 22] = sum;
    fl[(wv*16 + lr)*33 + 23] = ssq;
  }
  __syncthreads();
  // store: per instruction, 64 lanes = 64 consecutive rows of one j-plane
#pragma unroll
  for (int q = 0; q < 6; ++q) {
    const int o   = q*256 + t;            // 0..1535
    const int j   = o >> 6;               // 0..23
    const int row = o & 63;
    dotsp[(((size_t)kpart*24 + j)*NN + n)*RR + p0 + row] = fl[row*33 + j];
  }
}

// K2: one thread per position. Sums the 2 kpart partials, then softmax
// pass-1 weights, pass-2 logit pieces.
__global__ __launch_bounds__(256) void coef_kernel(
    const float* __restrict__ dotsp, const float* __restrict__ scal,
    float* __restrict__ pack)
{
  const int p = blockIdx.x*256 + threadIdx.x;      // 8192 threads exactly
  const float* dp0 = dotsp;
  const float* dp1 = dotsp + (size_t)24*NN*RR;
  float mu[NN], rs[NN];
#pragma unroll
  for (int n = 0; n < NN; ++n) {
    float s  = dp0[((size_t)22*NN + n)*RR + p] + dp1[((size_t)22*NN + n)*RR + p];
    float q2 = dp0[((size_t)23*NN + n)*RR + p] + dp1[((size_t)23*NN + n)*RR + p];
    mu[n] = s * (1.f/DD);
    rs[n] = rsqrtf(q2*(1.f/DD) - mu[n]*mu[n] + EPSV);
  }
  float* pk = pack + (size_t)p*264;
  for (int i = 0; i < NN; ++i) {                   // uniform runtime i
    const float qgA = scal[2*i],        qbA = scal[2*i+1];
    const float qgM = scal[2*(NN+i)],   qbM = scal[2*(NN+i)+1];
    float w1[NN];
    float mx = -3.0e38f;
#pragma unroll
    for (int n = 0; n < NN; ++n) if (n <= i) {
      float dA = dp0[((size_t)i*NN + n)*RR + p] + dp1[((size_t)i*NN + n)*RR + p];
      float lg = (dA - mu[n]*qgA)*rs[n] + qbA;
      w1[n] = lg;
      mx = fmaxf(mx, lg);
    }
    float S = 0.f;
#pragma unroll
    for (int n = 0; n < NN; ++n) if (n <= i) { float e = __expf(w1[n]-mx); w1[n] = e; S += e; }
    float inv = 1.f/S;
    float muh = 0.f, hd = 0.f;
#pragma unroll
    for (int n = 0; n < NN; ++n) if (n <= i) {
      w1[n] *= inv;
      float dM = dp0[((size_t)(NN+i)*NN + n)*RR + p] + dp1[((size_t)(NN+i)*NN + n)*RR + p];
      muh += w1[n]*mu[n];
      hd  += w1[n]*dM;
      pk[i*NN + n] = w1[n];
      if (n < i) pk[121 + i*NN + n] = (dM - mu[n]*qgM)*rs[n] + qbM;
    }
    pk[242 + i] = hd - muh*qgM;
    pk[253 + i] = muh;
  }
}

// K3: one block per position: h sumsq (11 wave reduces), finish logits,
// build C row, combine to out.
__global__ __launch_bounds__(256) void combine_kernel(
    const float* __restrict__ streams,
    const float* __restrict__ pack,
    const float* __restrict__ scal,
    float* __restrict__ out)
{
  __shared__ float P[264];
  __shared__ float red[4][12];
  __shared__ float C[121];

  const int p = blockIdx.x;
  const int t = threadIdx.x;
  const int lane = t & 63, w = t >> 6;

  for (int s = t; s < 264; s += 256) P[s] = pack[(size_t)p*264 + s];

  float4 x[NN];
#pragma unroll
  for (int n = 0; n < NN; ++n)
    x[n] = *(const float4*)(streams + ((size_t)n*RR + p)*DD + 4*t);
  __syncthreads();

  float hss[NN];
#pragma unroll
  for (int i = 0; i < NN; ++i) {
    float4 h = make_float4(0.f,0.f,0.f,0.f);
#pragma unroll
    for (int n = 0; n < NN; ++n) if (n <= i) {
      float wv = P[i*NN + n];
      h.x = fmaf(wv, x[n].x, h.x);
      h.y = fmaf(wv, x[n].y, h.y);
      h.z = fmaf(wv, x[n].z, h.z);
      h.w = fmaf(wv, x[n].w, h.w);
    }
    hss[i] = dot4(h, h);
  }
#pragma unroll
  for (int i = 0; i < NN; ++i) hss[i] = wave_reduce(hss[i]);
  if (lane == 0) {
#pragma unroll
    for (int i = 0; i < NN; ++i) red[w][i] = hss[i];
  }
  __syncthreads();

  if (t < NN) {
    const int i = t;
    float hs   = red[0][i] + red[1][i] + red[2][i] + red[3][i];
    float mu_h = P[253 + i];
    float Ahd  = P[242 + i];
    float varh = hs*(1.f/DD) - mu_h*mu_h;
    float rsh  = rsqrtf(varh + EPSV);
    float qbM  = scal[2*(NN+i)+1];
    float lgh  = Ahd*rsh + qbM;

    float mx2 = lgh;
#pragma unroll
    for (int n = 0; n < NN; ++n) if (n < i) mx2 = fmaxf(mx2, P[121 + i*NN + n]);
    float w2[NN];
    float eh = __expf(lgh - mx2);
    float S2 = eh;
#pragma unroll
    for (int n = 0; n < NN; ++n) if (n < i) {
      float e = __expf(P[121 + i*NN + n] - mx2);
      w2[n] = e;
      S2 += e;
    }
    float inv2 = 1.f/S2;
    float ehw  = eh*inv2;
#pragma unroll
    for (int n = 0; n < NN; ++n) {
      float cc = 0.f;
      if (n < i)  cc = w2[n]*inv2;
      if (n <= i) cc += ehw*P[i*NN + n];
      C[i*NN + n] = cc;
    }
  }
  __syncthreads();

#pragma unroll
  for (int i = 0; i < NN; ++i) {
    float4 o = make_float4(0.f,0.f,0.f,0.f);
#pragma unroll
    for (int n = 0; n < NN; ++n) {
      float cc = C[i*NN + n];
      o.x = fmaf(cc, x[n].x, o.x);
      o.y = fmaf(cc, x[n].y, o.y);
      o.z = fmaf(cc, x[n].z, o.z);
      o.w = fmaf(cc, x[n].w, o.w);
    }
    *(float4*)(out + ((size_t)i*RR + p)*DD + 4*t) = o;
  }
}

extern "C" void kernel_launch(void* const* d_in, const int* in_sizes, int n_in,
                              void* d_out, int out_size, void* d_ws, size_t ws_size,
                              hipStream_t stream) {
  const float* streams = (const float*)d_in[0];
  const float* aq = (const float*)d_in[1];
  const float* ag = (const float*)d_in[2];
  const float* ab = (const float*)d_in[3];
  const float* mq = (const float*)d_in[4];
  const float* mg = (const float*)d_in[5];
  const float* mb = (const float*)d_in[6];
  float* outp = (float*)d_out;

  float* wsf   = (float*)d_ws;
  float* wvec  = wsf;
  float* scal  = wsf + OFF_SCAL;
  short* wfrag = (short*)(wsf + OFF_WFRAG);
  float* dotsp = wsf + OFF_DOTS;
  float* pack  = wsf + OFF_PACK;

  prep_kernel<<<dim3(2*NN), dim3(PREP_TPB), 0, stream>>>(aq, ag, ab, mq, mg, mb, wvec, scal);
  prep2_kernel<<<dim3(32), dim3(256), 0, stream>>>(wvec, wfrag);
  dots_kernel<<<dim3(NN*128*KPARTS), dim3(256), 0, stream>>>(streams, wfrag, dotsp);
  coef_kernel<<<dim3(RR/256), dim3(256), 0, stream>>>(dotsp, scal, pack);
  combine_kernel<<<dim3(RR), dim3(256), 0, stream>>>(streams, pack, scal, outp);
}

// Round 14
// 254.332 us; speedup vs baseline: 1.2020x; 1.0284x over previous
//
#include <hip/hip_runtime.h>
#include <math.h>

#define NN 11
#define RR 8192               // B*L positions
#define DD 1024
#define EPSV 1e-5f
#define PREP_TPB 256

// ---- ws layout (floats) ----
// wvec  : [22][1024] f32   @ 0
// scal  : [22][2]    f32   @ 22528 (padded to 64)
// wfrag : [32][2][64][8] bf16 @ 22592 (32768 shorts = 16384 float-slots)
// dotsp : [KP][24][11][8192] @ 38976  (per-kpart partials; j:0..21, 22 sum, 23 ssq)
// pack  : [8192][264]        @ 38976 + KP*2162688
#define OFF_SCAL 22528
#define OFF_WFRAG 22592
#define OFF_DOTS 38976
#define PLANE 2162688          // 24*11*8192

typedef __attribute__((ext_vector_type(8))) short short8;
typedef __attribute__((ext_vector_type(4))) float f32x4;

__device__ __forceinline__ float wave_reduce(float v) {
#pragma unroll
  for (int o = 32; o > 0; o >>= 1) v += __shfl_xor(v, o, 64);
  return v;
}

__device__ __forceinline__ float dot4(const float4 a, const float4 b) {
  return a.x*b.x + a.y*b.y + a.z*b.z + a.w*b.w;
}

__device__ __forceinline__ unsigned bf2(float a, float b) {
  unsigned ua = __float_as_uint(a), ub = __float_as_uint(b);
  ua = (ua + 0x7FFFu + ((ua >> 16) & 1u)) >> 16;
  ub = (ub + 0x7FFFu + ((ub >> 16) & 1u)) >> 16;
  return ua | (ub << 16);
}

__global__ __launch_bounds__(PREP_TPB) void prep_kernel(
    const float* __restrict__ aq, const float* __restrict__ ag, const float* __restrict__ ab,
    const float* __restrict__ mq, const float* __restrict__ mg, const float* __restrict__ mb,
    float* __restrict__ wvec, float* __restrict__ scal)
{
  const int j = blockIdx.x;              // 0..21
  const float *q, *g, *bt;
  if (j < NN) { q = aq + (size_t)j*DD;      g = ag + (size_t)j*DD;      bt = ab + (size_t)j*DD; }
  else        { q = mq + (size_t)(j-NN)*DD; g = mg + (size_t)(j-NN)*DD; bt = mb + (size_t)(j-NN)*DD; }
  const int t = threadIdx.x;
  float sqg = 0.f, sqb = 0.f;
  for (int d = t; d < DD; d += PREP_TPB) {
    float qq = q[d];
    float w  = qq * g[d];
    wvec[(size_t)j*DD + d] = w;
    sqg += w;
    sqb += qq * bt[d];
  }
  sqg = wave_reduce(sqg);
  sqb = wave_reduce(sqb);
  __shared__ float red[2][PREP_TPB/64];
  const int lane = t & 63, wid = t >> 6;
  if (lane == 0) { red[0][wid] = sqg; red[1][wid] = sqb; }
  __syncthreads();
  if (t == 0) {
    float a = 0.f, b2 = 0.f;
    for (int w = 0; w < PREP_TPB/64; ++w) { a += red[0][w]; b2 += red[1][w]; }
    scal[2*j]   = a;
    scal[2*j+1] = b2;
  }
}

// pack B fragments: wfrag[kstep][c][lane][e] = bf16(wvec[j][k]), j=c*16+(lane&15),
// k=kstep*32+(lane>>4)*8+e; j>=22 -> 0.
__global__ __launch_bounds__(256) void prep2_kernel(
    const float* __restrict__ wvec, short* __restrict__ wfrag)
{
  const int kstep = blockIdx.x;          // 0..31
  const int t = threadIdx.x;
#pragma unroll
  for (int q = 0; q < 4; ++q) {
    const int idx  = t*4 + q;            // 0..1023
    const int c    = idx >> 9;
    const int lane = (idx >> 3) & 63;
    const int e    = idx & 7;
    const int k    = kstep*32 + (lane >> 4)*8 + e;
    const int j    = c*16 + (lane & 15);
    float v = (j < 22) ? wvec[(size_t)j*DD + k] : 0.f;
    unsigned u = __float_as_uint(v);
    u = (u + 0x7FFFu + ((u >> 16) & 1u)) >> 16;
    wfrag[(size_t)kstep*1024 + idx] = (short)u;
  }
}

// K1: MFMA dots, no stream staging. Block = (n, 64 pos, kpart of K=DD/KP).
// A-frags gathered from global with depth-2 prefetch; B slice in LDS
// (KSTEPS*2KB). Zero barriers in the K loop. Stats ride the A registers.
template<int KP>
__global__ __launch_bounds__(256) void dots_kernel(
    const float* __restrict__ streams, const short* __restrict__ wfrag,
    float* __restrict__ dotsp)
{
  constexpr int KSTEPS = (DD/KP)/32;     // 8 (KP=4) or 16 (KP=2)
  __shared__ __align__(16) short lwf[KSTEPS*1024];

  const int bid   = blockIdx.x;          // NN*128*KP
  const int n     = bid / (128*KP);
  const int rem   = bid % (128*KP);
  const int p0    = (rem / KP) * 64;
  const int kpart = rem % KP;
  const int t  = threadIdx.x;
  const int l  = t & 63;
  const int wv = t >> 6;                 // wave 0..3 -> rows [16wv,16wv+16)
  const int lr = l & 15;
  const int g  = l >> 4;                 // 0..3

  // ---- preload B slice into LDS (coalesced) ----
  {
    const short8* src = (const short8*)(wfrag + (size_t)kpart*(KSTEPS*1024));
    short8* dst = (short8*)lwf;
#pragma unroll
    for (int q = 0; q < KSTEPS/2; ++q) dst[t*(KSTEPS/2) + q] = src[t*(KSTEPS/2) + q];
  }
  __syncthreads();

  const float* rowp = streams + ((size_t)(n*RR + p0 + wv*16 + lr))*DD + kpart*(DD/KP);

  f32x4 acc0 = {0.f,0.f,0.f,0.f};
  f32x4 acc1 = {0.f,0.f,0.f,0.f};
  float sum = 0.f, ssq = 0.f;

#define LDA(ks,h) (*(const float4*)(rowp + (ks)*32 + g*8 + (h)*4))
  float4 c0 = LDA(0,0), c1 = LDA(0,1);
  float4 d0 = LDA(1,0), d1 = LDA(1,1);

#pragma unroll
  for (int ks = 0; ks < KSTEPS; ++ks) {
    float4 e0, e1;
    if (ks + 2 < KSTEPS) { e0 = LDA(ks+2,0); e1 = LDA(ks+2,1); }
    // stats (f32 exact)
    sum += c0.x + c0.y + c0.z + c0.w + c1.x + c1.y + c1.z + c1.w;
    ssq = fmaf(c0.x,c0.x, ssq); ssq = fmaf(c0.y,c0.y, ssq);
    ssq = fmaf(c0.z,c0.z, ssq); ssq = fmaf(c0.w,c0.w, ssq);
    ssq = fmaf(c1.x,c1.x, ssq); ssq = fmaf(c1.y,c1.y, ssq);
    ssq = fmaf(c1.z,c1.z, ssq); ssq = fmaf(c1.w,c1.w, ssq);
    // cvt to bf16 A-frag
    union { short8 s; uint4 u; } cv;
    cv.u = make_uint4(bf2(c0.x,c0.y), bf2(c0.z,c0.w), bf2(c1.x,c1.y), bf2(c1.z,c1.w));
    // B frags from LDS (16B/lane, conflict-free)
    short8 b0 = *(const short8*)(lwf + ks*1024 + l*8);
    short8 b1 = *(const short8*)(lwf + ks*1024 + 512 + l*8);
    acc0 = __builtin_amdgcn_mfma_f32_16x16x32_bf16(cv.s, b0, acc0, 0, 0, 0);
    acc1 = __builtin_amdgcn_mfma_f32_16x16x32_bf16(cv.s, b1, acc1, 0, 0, 0);
    c0 = d0; c1 = d1; d0 = e0; d1 = e1;
  }
#undef LDA

  // ---- stats: reduce over the 4 k-slice lanes (l, l^16, l^32, l^48) ----
  sum += __shfl_xor(sum, 16, 64); sum += __shfl_xor(sum, 32, 64);
  ssq += __shfl_xor(ssq, 16, 64); ssq += __shfl_xor(ssq, 32, 64);

  // ---- epilogue: C + stats -> fl[64][33] in reused LDS, coalesced store ----
  __syncthreads();                        // all waves done reading lwf
  float* fl = (float*)lwf;
#pragma unroll
  for (int r = 0; r < 4; ++r) {
    fl[(wv*16 + g*4 + r)*33 + lr]      = acc0[r];
    fl[(wv*16 + g*4 + r)*33 + 16 + lr] = acc1[r];
  }
  if (g == 0) {
    fl[(wv*16 + lr)*33 + 22] = sum;
    fl[(wv*16 + lr)*33 + 23] = ssq;
  }
  __syncthreads();
#pragma unroll
  for (int q = 0; q < 6; ++q) {
    const int o   = q*256 + t;            // 0..1535
    const int j   = o >> 6;               // 0..23
    const int row = o & 63;
    dotsp[(((size_t)kpart*24 + j)*NN + n)*RR + p0 + row] = fl[row*33 + j];
  }
}

// K2: thread per (position, i). Sums KP kpart partials; softmax pass-1
// weights, pass-2 logit pieces for its own i. Coalesced in p.
template<int KP>
__global__ __launch_bounds__(256) void coef_kernel(
    const float* __restrict__ dotsp, const float* __restrict__ scal,
    float* __restrict__ pack)
{
  const int i = blockIdx.x >> 5;                   // 0..10
  const int p = (blockIdx.x & 31)*256 + threadIdx.x;

  float mu[NN], rs[NN];
#pragma unroll
  for (int n = 0; n < NN; ++n) {
    float s = 0.f, q2 = 0.f;
#pragma unroll
    for (int kp = 0; kp < KP; ++kp) {
      s  += dotsp[(((size_t)kp*24 + 22)*NN + n)*RR + p];
      q2 += dotsp[(((size_t)kp*24 + 23)*NN + n)*RR + p];
    }
    mu[n] = s * (1.f/DD);
    rs[n] = rsqrtf(q2*(1.f/DD) - mu[n]*mu[n] + EPSV);
  }

  const float qgA = scal[2*i],        qbA = scal[2*i+1];
  const float qgM = scal[2*(NN+i)],   qbM = scal[2*(NN+i)+1];
  float* pk = pack + (size_t)p*264;

  float w1[NN], dM[NN];
  float mx = -3.0e38f;
#pragma unroll
  for (int n = 0; n < NN; ++n) if (n <= i) {
    float dA = 0.f, dm = 0.f;
#pragma unroll
    for (int kp = 0; kp < KP; ++kp) {
      dA += dotsp[(((size_t)kp*24 + i)*NN + n)*RR + p];
      dm += dotsp[(((size_t)kp*24 + NN + i)*NN + n)*RR + p];
    }
    dM[n] = dm;
    float lg = (dA - mu[n]*qgA)*rs[n] + qbA;
    w1[n] = lg;
    mx = fmaxf(mx, lg);
  }
  float S = 0.f;
#pragma unroll
  for (int n = 0; n < NN; ++n) if (n <= i) { float e = __expf(w1[n]-mx); w1[n] = e; S += e; }
  float inv = 1.f/S;
  float muh = 0.f, hd = 0.f;
#pragma unroll
  for (int n = 0; n < NN; ++n) if (n <= i) {
    w1[n] *= inv;
    muh += w1[n]*mu[n];
    hd  += w1[n]*dM[n];
    pk[i*NN + n] = w1[n];
    if (n < i) pk[121 + i*NN + n] = (dM[n] - mu[n]*qgM)*rs[n] + qbM;
  }
  pk[242 + i] = hd - muh*qgM;
  pk[253 + i] = muh;
}

// K3: one block per position: h sumsq (11 wave reduces), finish logits,
// build C row, combine to out.
__global__ __launch_bounds__(256) void combine_kernel(
    const float* __restrict__ streams,
    const float* __restrict__ pack,
    const float* __restrict__ scal,
    float* __restrict__ out)
{
  __shared__ float P[264];
  __shared__ float red[4][12];
  __shared__ float C[121];

  const int p = blockIdx.x;
  const int t = threadIdx.x;
  const int lane = t & 63, w = t >> 6;

  for (int s = t; s < 264; s += 256) P[s] = pack[(size_t)p*264 + s];

  float4 x[NN];
#pragma unroll
  for (int n = 0; n < NN; ++n)
    x[n] = *(const float4*)(streams + ((size_t)n*RR + p)*DD + 4*t);
  __syncthreads();

  float hss[NN];
#pragma unroll
  for (int i = 0; i < NN; ++i) {
    float4 h = make_float4(0.f,0.f,0.f,0.f);
#pragma unroll
    for (int n = 0; n < NN; ++n) if (n <= i) {
      float wv = P[i*NN + n];
      h.x = fmaf(wv, x[n].x, h.x);
      h.y = fmaf(wv, x[n].y, h.y);
      h.z = fmaf(wv, x[n].z, h.z);
      h.w = fmaf(wv, x[n].w, h.w);
    }
    hss[i] = dot4(h, h);
  }
#pragma unroll
  for (int i = 0; i < NN; ++i) hss[i] = wave_reduce(hss[i]);
  if (lane == 0) {
#pragma unroll
    for (int i = 0; i < NN; ++i) red[w][i] = hss[i];
  }
  __syncthreads();

  if (t < NN) {
    const int i = t;
    float hs   = red[0][i] + red[1][i] + red[2][i] + red[3][i];
    float mu_h = P[253 + i];
    float Ahd  = P[242 + i];
    float varh = hs*(1.f/DD) - mu_h*mu_h;
    float rsh  = rsqrtf(varh + EPSV);
    float qbM  = scal[2*(NN+i)+1];
    float lgh  = Ahd*rsh + qbM;

    float mx2 = lgh;
#pragma unroll
    for (int n = 0; n < NN; ++n) if (n < i) mx2 = fmaxf(mx2, P[121 + i*NN + n]);
    float w2[NN];
    float eh = __expf(lgh - mx2);
    float S2 = eh;
#pragma unroll
    for (int n = 0; n < NN; ++n) if (n < i) {
      float e = __expf(P[121 + i*NN + n] - mx2);
      w2[n] = e;
      S2 += e;
    }
    float inv2 = 1.f/S2;
    float ehw  = eh*inv2;
#pragma unroll
    for (int n = 0; n < NN; ++n) {
      float cc = 0.f;
      if (n < i)  cc = w2[n]*inv2;
      if (n <= i) cc += ehw*P[i*NN + n];
      C[i*NN + n] = cc;
    }
  }
  __syncthreads();

#pragma unroll
  for (int i = 0; i < NN; ++i) {
    float4 o = make_float4(0.f,0.f,0.f,0.f);
#pragma unroll
    for (int n = 0; n < NN; ++n) {
      float cc = C[i*NN + n];
      o.x = fmaf(cc, x[n].x, o.x);
      o.y = fmaf(cc, x[n].y, o.y);
      o.z = fmaf(cc, x[n].z, o.z);
      o.w = fmaf(cc, x[n].w, o.w);
    }
    *(float4*)(out + ((size_t)i*RR + p)*DD + 4*t) = o;
  }
}

extern "C" void kernel_launch(void* const* d_in, const int* in_sizes, int n_in,
                              void* d_out, int out_size, void* d_ws, size_t ws_size,
                              hipStream_t stream) {
  const float* streams = (const float*)d_in[0];
  const float* aq = (const float*)d_in[1];
  const float* ag = (const float*)d_in[2];
  const float* ab = (const float*)d_in[3];
  const float* mq = (const float*)d_in[4];
  const float* mg = (const float*)d_in[5];
  const float* mb = (const float*)d_in[6];
  float* outp = (float*)d_out;

  float* wsf   = (float*)d_ws;
  float* wvec  = wsf;
  float* scal  = wsf + OFF_SCAL;
  short* wfrag = (short*)(wsf + OFF_WFRAG);
  float* dotsp = wsf + OFF_DOTS;

  const size_t need4 = ((size_t)OFF_DOTS + 4*(size_t)PLANE + 8192*264) * 4;
  const int KP = (ws_size >= need4) ? 4 : 2;
  float* pack = wsf + OFF_DOTS + (size_t)KP*PLANE;

  prep_kernel<<<dim3(2*NN), dim3(PREP_TPB), 0, stream>>>(aq, ag, ab, mq, mg, mb, wvec, scal);
  prep2_kernel<<<dim3(32), dim3(256), 0, stream>>>(wvec, wfrag);
  if (KP == 4) {
    dots_kernel<4><<<dim3(NN*128*4), dim3(256), 0, stream>>>(streams, wfrag, dotsp);
    coef_kernel<4><<<dim3(NN*32), dim3(256), 0, stream>>>(dotsp, scal, pack);
  } else {
    dots_kernel<2><<<dim3(NN*128*2), dim3(256), 0, stream>>>(streams, wfrag, dotsp);
    coef_kernel<2><<<dim3(NN*32), dim3(256), 0, stream>>>(dotsp, scal, pack);
  }
  combine_kernel<<<dim3(RR), dim3(256), 0, stream>>>(streams, pack, scal, outp);
}